// Round 1
// 115.780 us; speedup vs baseline: 1.0078x; 1.0078x over previous
//
#include <hip/hip_runtime.h>
#include <math.h>

// Problem constants (fixed by setup_inputs)
#define BB   16
#define HW   65536          // 256*256
#define NPIX (BB * HW)      // 1,048,576
#define NT   256
#define PPT  2              // 2 pixels/thread: 20.6 KB LDS, identity staging
#define NBLK (NPIX / (NT * PPT))   // 2048 blocks
#define BPI  (NBLK / BB)           // 128 blocks per image

// ws layout (bytes)
#define UARR_OFF  0ull                              // 4 MB
#define CLSL_OFF  (4ull << 20)                      // 4 MB
// 8 partial arrays of NBLK floats (plain stores, no atomics):
//  0 pos  1 neg  2 s1  3 m1  4 s0  5 m0  6 wcl  7 negsum(=sum clsl over neg)
#define PART_OFF  (8ull << 20)                      // 8*2048*4 = 64 KB
#define STATS_OFF ((8ull << 20) + (64ull << 10))
#define CTR_OFF   ((8ull << 20) + (128ull << 10))   // 1 u32 arrival counter

// stats layout (index into float/u32 view)
#define S_NPOS    0    // [16] u32 per-image pos count
#define F_SELCNT  16   // [16] float per-image selected-neg count
#define F_SELSUM  32   // [16] float per-image sum(clsl over selected)
#define F_GLB     48   // [5] float: s1,m1,s0,m0,wcl

// monotone unsigned mapping of float bits (ascending float -> ascending uint)
__device__ __forceinline__ unsigned fmap(float x) {
  unsigned b = __float_as_uint(x);
  return (b & 0x80000000u) ? ~b : (b | 0x80000000u);
}

// log(1 + e^{-|d|}) with native exp/log: arg of log is in (1,2] -> accurate
__device__ __forceinline__ float softplus_neg_abs(float d) {
  return __logf(1.f + __expf(-fabsf(d)));
}

// Crossing search for rank k in an LDS histogram (nbins multiple of 256).
__device__ __forceinline__ void histSelect(unsigned* lhist, int nbins, unsigned k,
                                           unsigned* wt, unsigned* sh_bin,
                                           unsigned* sh_rank) {
  int lane = threadIdx.x & 63, wave = threadIdx.x >> 6;
  int per = nbins >> 8;
  unsigned s = 0;
  for (int j = 0; j < per; j++) s += lhist[threadIdx.x * per + j];
  unsigned x = s;
  for (int o = 1; o < 64; o <<= 1) { unsigned v = __shfl_up(x, o, 64); if (lane >= o) x += v; }
  if (lane == 63) wt[wave] = x;
  __syncthreads();
  unsigned woff = 0;
  for (int w = 0; w < wave; w++) woff += wt[w];
  unsigned incl = x + woff, excl = incl - s;
  if (excl < k && k <= incl) {
    unsigned cum = excl;
    for (int j = 0; j < per; j++) {
      unsigned c = lhist[threadIdx.x * per + j];
      if (k <= cum + c) { *sh_bin = (unsigned)(threadIdx.x * per + j); *sh_rank = k - cum; break; }
      cum += c;
    }
  }
  __syncthreads();
}

// kA: one per-pixel pass, 2 pixels/thread.
//  - target (pixel-major, 40 B/pixel) staged through LDS; with PPT=2 the
//    chunk->group scatter is the IDENTITY, so staging is a linear copy.
//    Group stride = 20 words -> base banks 20*t mod 32 cycle through 8
//    distinct bank-quads -> conflict-free float4 writes AND b128 reads.
//  - logits loads are float2 per channel, perfectly coalesced.
//  - 20.6 KB LDS + ~halved register arrays -> ~5 blocks/CU (vs 3 before)
//    for latency hiding; kernel is memory-bound (~15 us traffic floor).
__global__ __launch_bounds__(NT, 4) void kA(
    const float* __restrict__ target, const float* __restrict__ logits,
    unsigned* __restrict__ uarr, float* __restrict__ clsl,
    float* __restrict__ part, unsigned* __restrict__ ctr) {
  __shared__ float4 sT4[NT * 5];       // 20480 B, linear chunk order
  __shared__ float red[8][4];
  if (blockIdx.x == 0 && threadIdx.x == 0) ctr[0] = 0u;   // arrival ctr for kThresh

  const int P0 = blockIdx.x * (NT * PPT);   // block's first pixel
  const int p0 = P0 + threadIdx.x * PPT;    // thread's 2 consecutive pixels
  const int b  = P0 >> 16;                  // 512 | 65536 -> one image per block
  const int hw = p0 & 65535;
  const int lane = threadIdx.x & 63, wave = threadIdx.x >> 6;

  // logits: 10 channels, float2 per channel (8 B/lane, coalesced)
  const float* lg = logits + (size_t)b * 10 * HW + hw;
  float2 L[10];
#pragma unroll
  for (int c = 0; c < 10; c++) L[c] = *(const float2*)(lg + (size_t)c * HW);

  // target: block's 512 pixels = 1280 contiguous float4, linear LDS stage
  const float4* tBase = (const float4*)(target + (size_t)P0 * 10);
  float4 T[5];
#pragma unroll
  for (int j = 0; j < 5; j++) T[j] = tBase[threadIdx.x + NT * j];
#pragma unroll
  for (int j = 0; j < 5; j++) sT4[threadIdx.x + NT * j] = T[j];
  __syncthreads();

  float tf[20];
#pragma unroll
  for (int m = 0; m < 5; m++) {
    float4 v = sT4[5 * threadIdx.x + m];   // stride 20 words: conflict-free
    tf[4 * m] = v.x; tf[4 * m + 1] = v.y; tf[4 * m + 2] = v.z; tf[4 * m + 3] = v.w;
  }

  float cpos = 0.f, cneg = 0.f, s1 = 0.f, m1 = 0.f, s0 = 0.f, m0 = 0.f, wcl = 0.f;
  float negsum = 0.f;
  float cl2[2];
  unsigned uu[2];
#pragma unroll
  for (int q = 0; q < PPT; q++) {
    float label = tf[10 * q];
    float wgt   = tf[10 * q + 1];
    bool pos = label > 0.f;
    bool neg = label == 0.f;
    float l0 = q ? L[0].y : L[0].x;
    float l1 = q ? L[1].y : L[1].x;
    float d = l0 - l1;
    float cl = fmaxf(l0, l1) + softplus_neg_abs(d) - (pos ? l1 : l0);
    cl2[q] = cl;
    wcl += cl * wgt;
    cpos += pos ? 1.f : 0.f;
    cneg += neg ? 1.f : 0.f;
    if (neg) negsum += cl;
    unsigned u = fmap(d);              // score = sigmoid(d) monotone in d
    uu[q] = neg ? u : 0xFFFFFFFFu;     // finite d never maps to 0xFFFFFFFF
#pragma unroll
    for (int n = 0; n < 4; n++) {
      float a = q ? L[2 + n].y : L[2 + n].x;   // class-0 logit
      float c = q ? L[6 + n].y : L[6 + n].x;   // class-1 logit
      float ce0 = fmaxf(a, c) + softplus_neg_abs(a - c);
      int lab = (int)tf[10 * q + 2 + n];
      float ce = ce0 - (lab ? c : a);
      float w = tf[10 * q + 6 + n];
      if (lab) { m1 += w; s1 += w * ce; }
      else     { m0 += w; s0 += w * ce; }
    }
  }
  *(float2*)(clsl + p0) = make_float2(cl2[0], cl2[1]);
  *(uint2*)(uarr + p0)  = make_uint2(uu[0], uu[1]);

  float vals[8] = {cpos, cneg, s1, m1, s0, m0, wcl, negsum};
#pragma unroll
  for (int qq = 0; qq < 8; qq++) {
    float x = vals[qq];
    for (int o = 32; o; o >>= 1) x += __shfl_down(x, o, 64);
    if (lane == 0) red[qq][wave] = x;
  }
  __syncthreads();
  if (threadIdx.x < 8)
    part[(size_t)threadIdx.x * NBLK + blockIdx.x] =
        red[threadIdx.x][0] + red[threadIdx.x][1] + red[threadIdx.x][2] + red[threadIdx.x][3];
}

// kThresh: 16 blocks, one per image. Reduce per-image partials; OHEM shortcut
// or exact in-LDS 3-level radix select + image scan. Block 0 also reduces the
// 5 global float slots. 16-block arrival; last block assembles both outputs.
__global__ void kThresh(const unsigned* __restrict__ uarr, const float* __restrict__ clsl,
                        const float* __restrict__ part, unsigned* __restrict__ stats,
                        unsigned* __restrict__ ctr, float* __restrict__ out) {
  __shared__ unsigned lhist[4096];
  __shared__ unsigned wt[4];
  __shared__ unsigned shb, shr;
  __shared__ float shv[3];
  __shared__ float red2[5][4];
  __shared__ unsigned sh_t;
  const int img = blockIdx.x;
  const int lane = threadIdx.x & 63, wave = threadIdx.x >> 6;
  float* fstats = (float*)stats;

  // per-image reductions of slots 0 (pos), 1 (neg), 7 (negsum): 128 values each
  if (threadIdx.x < 64) {
    int base = img * BPI + threadIdx.x;
    float cp = part[0 * NBLK + base] + part[0 * NBLK + base + 64];
    float cn = part[1 * NBLK + base] + part[1 * NBLK + base + 64];
    float ns = part[7 * NBLK + base] + part[7 * NBLK + base + 64];
    for (int o = 32; o; o >>= 1) {
      cp += __shfl_down(cp, o, 64);
      cn += __shfl_down(cn, o, 64);
      ns += __shfl_down(ns, o, 64);
    }
    if (threadIdx.x == 0) { shv[0] = cp; shv[1] = cn; shv[2] = ns; }
  }
  // block 0: reduce global slots 2..6 (s1,m1,s0,m0,wcl) over NBLK
  if (img == 0) {
#pragma unroll
    for (int s = 0; s < 5; s++) {
      const float* p = part + (size_t)(2 + s) * NBLK;
      float x = 0.f;
      for (int t = threadIdx.x; t < NBLK; t += NT) x += p[t];
      for (int o = 32; o; o >>= 1) x += __shfl_down(x, o, 64);
      if (lane == 0) red2[s][wave] = x;
    }
  }
  __syncthreads();
  if (img == 0 && threadIdx.x < 5)
    fstats[F_GLB + threadIdx.x] = red2[threadIdx.x][0] + red2[threadIdx.x][1] +
                                  red2[threadIdx.x][2] + red2[threadIdx.x][3];

  unsigned npos = (unsigned)(shv[0] + 0.5f);
  unsigned nneg = (unsigned)(shv[1] + 0.5f);
  float negsum = shv[2];
  if (threadIdx.x == 0) stats[S_NPOS + img] = npos;

  unsigned k = min(3u * npos, nneg);
  if (npos == 0u || k == 0u || k >= nneg) {
    // use_all OR k==n_neg (thr = max neg score): select ALL negatives.
    if (threadIdx.x == 0) { fstats[F_SELCNT + img] = (float)nneg; fstats[F_SELSUM + img] = negsum; }
  } else {
    // exact k-th smallest of this image's 64K u values (sentinels = +max).
    const uint4* u4 = (const uint4*)(uarr + (size_t)img * HW);
    // level 1: hi-12
    for (int j = threadIdx.x; j < 4096; j += NT) lhist[j] = 0;
    __syncthreads();
    for (int j = threadIdx.x; j < HW / 4; j += NT) {
      uint4 v = u4[j];
      atomicAdd(&lhist[v.x >> 20], 1u);
      atomicAdd(&lhist[v.y >> 20], 1u);
      atomicAdd(&lhist[v.z >> 20], 1u);
      atomicAdd(&lhist[v.w >> 20], 1u);
    }
    __syncthreads();
    histSelect(lhist, 4096, k, wt, &shb, &shr);
    unsigned B1 = shb, r1 = shr;
    // level 2: mid-12 within B1
    for (int j = threadIdx.x; j < 4096; j += NT) lhist[j] = 0;
    __syncthreads();
    for (int j = threadIdx.x; j < HW / 4; j += NT) {
      uint4 v = u4[j];
      if ((v.x >> 20) == B1) atomicAdd(&lhist[(v.x >> 8) & 0xFFFu], 1u);
      if ((v.y >> 20) == B1) atomicAdd(&lhist[(v.y >> 8) & 0xFFFu], 1u);
      if ((v.z >> 20) == B1) atomicAdd(&lhist[(v.z >> 8) & 0xFFFu], 1u);
      if ((v.w >> 20) == B1) atomicAdd(&lhist[(v.w >> 8) & 0xFFFu], 1u);
    }
    __syncthreads();
    histSelect(lhist, 4096, r1, wt, &shb, &shr);
    unsigned hi24 = (B1 << 12) | shb;
    unsigned r2 = shr;
    // level 3: low-8 within hi24
    for (int j = threadIdx.x; j < 256; j += NT) lhist[j] = 0;
    __syncthreads();
    for (int j = threadIdx.x; j < HW / 4; j += NT) {
      uint4 v = u4[j];
      if ((v.x >> 8) == hi24) atomicAdd(&lhist[v.x & 0xFFu], 1u);
      if ((v.y >> 8) == hi24) atomicAdd(&lhist[v.y & 0xFFu], 1u);
      if ((v.z >> 8) == hi24) atomicAdd(&lhist[v.z & 0xFFu], 1u);
      if ((v.w >> 8) == hi24) atomicAdd(&lhist[v.w & 0xFFu], 1u);
    }
    __syncthreads();
    histSelect(lhist, 256, r2, wt, &shb, &shr);
    unsigned thr = (hi24 << 8) | shb;
    // scan the image: selcnt = #{u <= thr}, selsum = sum clsl over selected
    const float4* c4 = (const float4*)(clsl + (size_t)img * HW);
    float cnt = 0.f, sum = 0.f;
    for (int j = threadIdx.x; j < HW / 4; j += NT) {
      uint4 v = u4[j];
      float4 c = c4[j];
      if (v.x <= thr) { cnt += 1.f; sum += c.x; }
      if (v.y <= thr) { cnt += 1.f; sum += c.y; }
      if (v.z <= thr) { cnt += 1.f; sum += c.z; }
      if (v.w <= thr) { cnt += 1.f; sum += c.w; }
    }
    for (int o = 32; o; o >>= 1) { cnt += __shfl_down(cnt, o, 64); sum += __shfl_down(sum, o, 64); }
    if (lane == 0) { red2[0][wave] = cnt; red2[1][wave] = sum; }
    __syncthreads();
    if (threadIdx.x == 0) {
      fstats[F_SELCNT + img] = red2[0][0] + red2[0][1] + red2[0][2] + red2[0][3];
      fstats[F_SELSUM + img] = red2[1][0] + red2[1][1] + red2[1][2] + red2[1][3];
    }
  }

  // 16-block arrival (cheap at this scale); last block assembles outputs.
  __threadfence();
  __syncthreads();
  if (threadIdx.x == 0) sh_t = atomicAdd(&ctr[0], 1u);
  __syncthreads();
  if (sh_t != BB - 1) return;
  __threadfence();
  if (threadIdx.x == 0) {
    unsigned npos_t = 0;
    float nsel = 0.f, selsum = 0.f;
    for (int b = 0; b < BB; b++) {
      npos_t += stats[S_NPOS + b];
      nsel   += fstats[F_SELCNT + b];
      selsum += fstats[F_SELSUM + b];
    }
    float s1 = fstats[F_GLB + 0], m1 = fstats[F_GLB + 1];
    float s0 = fstats[F_GLB + 2], m0 = fstats[F_GLB + 3];
    float wcl = fstats[F_GLB + 4];
    out[0] = 2.f * (wcl + selsum) / ((float)npos_t + nsel);
    out[1] = (npos_t != 0u) ? (s1 / m1 + s0 / m0) : 0.f;
  }
}

extern "C" void kernel_launch(void* const* d_in, const int* in_sizes, int n_in,
                              void* d_out, int out_size, void* d_ws, size_t ws_size,
                              hipStream_t stream) {
  const float* target = (const float*)d_in[0];   // (16,256,256,10)
  const float* logits = (const float*)d_in[1];   // (16,10,256,256)
  float* out = (float*)d_out;                    // [cls_loss*2, link_loss]
  char* ws = (char*)d_ws;

  unsigned* uarr  = (unsigned*)(ws + UARR_OFF);
  float*    clsl  = (float*)(ws + CLSL_OFF);
  float*    part  = (float*)(ws + PART_OFF);
  unsigned* stats = (unsigned*)(ws + STATS_OFF);
  unsigned* ctr   = (unsigned*)(ws + CTR_OFF);

  kA<<<NBLK, NT, 0, stream>>>(target, logits, uarr, clsl, part, ctr);
  kThresh<<<BB, NT, 0, stream>>>(uarr, clsl, part, stats, ctr, out);
}